// Round 10
// baseline (226.479 us; speedup 1.0000x reference)
//
#include <hip/hip_runtime.h>

// GCN layer: out = relu(x @ W_self^T + b_self + segment_mean(x[src], dst) @ W_neigh^T)
// N = 100000 nodes, D = 64, E = 1.25M edges.
//
// Pipeline:
//   x2bf        : one-time x fp32 -> bf16 (12.8 MB data plane).
//   bin_hist    : per-block LDS hist of 4096-edge chunk -> 1 atomic/(block,bucket).
//   bin_scan    : one-wave exclusive scan of the 98 bucket counts.
//   bin_scatter : LDS-staged radix scatter; every ebuf line written by ONE block.
//   sb_csr8     : 8 blocks per 1024-node bucket (784 blocks total). Single pass
//                 counts prefix-below-subrange + per-node counts for its 128
//                 nodes, then scatters -> exact CSR. Fixes r9's 98-block serialization.
//   gcn_gather  : one wave per node on bf16 rows (128B), 8 edges per dwordx4
//                 instruction, fp32 accumulate, bf16 agg write.
//   gcn_gemm    : bf16 MFMA (16x16x32), zero LDS; A-frags load DIRECTLY from
//                 bf16 x/agg; W packed from fp32 (L1-hot); bias+relu fused.

#define BKSH 10               // log2(nodes per bucket)
#define BKN 1024              // nodes per bucket
#define CHUNK 4096            // edges per binning block
#define MAXNB 128             // >= NB = ceil(N / BKN) = 98

typedef __attribute__((ext_vector_type(8))) short short8;
typedef __attribute__((ext_vector_type(4))) float floatx4;

// fp32 -> bf16 round-to-nearest-even, branch-free.
static __device__ inline unsigned short f2bf(float f) {
  union { float f; unsigned int u; } v;
  v.f = f;
  unsigned int r = v.u + 0x7FFFu + ((v.u >> 16) & 1u);
  return (unsigned short)(r >> 16);
}

static __device__ inline short8 pack8(float4 a, float4 b) {
  short8 s;
  s[0] = (short)f2bf(a.x); s[1] = (short)f2bf(a.y);
  s[2] = (short)f2bf(a.z); s[3] = (short)f2bf(a.w);
  s[4] = (short)f2bf(b.x); s[5] = (short)f2bf(b.y);
  s[6] = (short)f2bf(b.z); s[7] = (short)f2bf(b.w);
  return s;
}

// unpack 8 bf16 (as 4 dwords) and accumulate into 8 fp32: 2 VALU per 2 elems.
static __device__ inline void add8(float* a, short8 sv) {
  union { short8 s; unsigned int u[4]; } c; c.s = sv;
#pragma unroll
  for (int i = 0; i < 4; ++i) {
    a[2 * i]     += __uint_as_float(c.u[i] << 16);
    a[2 * i + 1] += __uint_as_float(c.u[i] & 0xFFFF0000u);
  }
}

__global__ __launch_bounds__(256) void x2bf(const float* __restrict__ x,
                                            unsigned short* __restrict__ xb,
                                            long long n) {
  long long i = ((long long)blockIdx.x * 256 + threadIdx.x) * 8;
  if (i < n) {
    float4 a = *(const float4*)&x[i];
    float4 b = *(const float4*)&x[i + 4];
    *(short8*)&xb[i] = pack8(a, b);
  }
}

__global__ __launch_bounds__(256) void bin_hist(const int* __restrict__ dst,
                                                int* __restrict__ gcnt, int E, int NB) {
  __shared__ int h[MAXNB];
  int t = threadIdx.x;
  if (t < MAXNB) h[t] = 0;
  __syncthreads();
  int base = blockIdx.x * CHUNK;
  if (base + CHUNK <= E) {
    const int4* d4 = (const int4*)(dst + base);
#pragma unroll
    for (int i = 0; i < 4; ++i) {
      int4 v = d4[t + 256 * i];
      atomicAdd(&h[v.x >> BKSH], 1);
      atomicAdd(&h[v.y >> BKSH], 1);
      atomicAdd(&h[v.z >> BKSH], 1);
      atomicAdd(&h[v.w >> BKSH], 1);
    }
  } else {
    for (int i = t; i < CHUNK; i += 256) {
      int e = base + i;
      if (e < E) atomicAdd(&h[dst[e] >> BKSH], 1);
    }
  }
  __syncthreads();
  if (t < NB && h[t]) atomicAdd(&gcnt[t], h[t]);
}

__global__ __launch_bounds__(64) void bin_scan(const int* __restrict__ gcnt,
                                               int* __restrict__ bstart,
                                               int* __restrict__ cursor, int NB, int E) {
  int t = threadIdx.x;
  int i0 = 2 * t, i1 = 2 * t + 1;
  int v0 = (i0 < NB) ? gcnt[i0] : 0;
  int v1 = (i1 < NB) ? gcnt[i1] : 0;
  int s = v0 + v1, inc = s;
#pragma unroll
  for (int off = 1; off < 64; off <<= 1) {
    int u = __shfl_up(inc, off, 64);
    if (t >= off) inc += u;
  }
  int ex = inc - s;
  if (i0 < NB) { bstart[i0] = ex;      cursor[i0] = ex; }
  if (i1 < NB) { bstart[i1] = ex + v0; cursor[i1] = ex + v0; }
  if (t == 0) bstart[NB] = E;
}

__global__ __launch_bounds__(256) void bin_scatter(const int* __restrict__ src,
                                                   const int* __restrict__ dst,
                                                   int* __restrict__ cursor,
                                                   int* __restrict__ ebuf, int E, int NB) {
  __shared__ int h[MAXNB], loff[MAXNB], gbase[MAXNB];
  __shared__ int sbuf[CHUNK];
  int t = threadIdx.x;
  if (t < MAXNB) h[t] = 0;
  __syncthreads();

  int base = blockIdx.x * CHUNK;
  int myd[CHUNK / 256], mys[CHUNK / 256];
#pragma unroll
  for (int i = 0; i < CHUNK / 256; ++i) {
    int e = base + t + 256 * i;  // coalesced
    if (e < E) {
      myd[i] = dst[e];
      mys[i] = src[e];
      atomicAdd(&h[myd[i] >> BKSH], 1);
    } else myd[i] = -1;
  }
  __syncthreads();

  if (t < 64) {  // wave 0: exclusive scan of h[0..127]
    int i0 = 2 * t, i1 = 2 * t + 1;
    int v0 = h[i0], v1 = h[i1];
    int s = v0 + v1, inc = s;
#pragma unroll
    for (int off = 1; off < 64; off <<= 1) {
      int u = __shfl_up(inc, off, 64);
      if (t >= off) inc += u;
    }
    int ex = inc - s;
    loff[i0] = ex; loff[i1] = ex + v0;
  }
  __syncthreads();

  if (t < NB) {
    if (h[t] > 0) gbase[t] = atomicAdd(&cursor[t], h[t]);  // claim contiguous run
  }
  if (t < MAXNB) h[t] = 0;  // reuse as local cursor
  __syncthreads();

#pragma unroll
  for (int i = 0; i < CHUNK / 256; ++i) {
    if (myd[i] >= 0) {
      int b = myd[i] >> BKSH;
      int p = atomicAdd(&h[b], 1);
      sbuf[loff[b] + p] = mys[i] | ((myd[i] & (BKN - 1)) << 17);  // src < 2^17
    }
  }
  __syncthreads();

  int w = t >> 6, lane = t & 63;
  for (int b = w; b < NB; b += 4) {
    int c = h[b], lo = loff[b], go = gbase[b];
    for (int j = lane; j < c; j += 64)
      ebuf[go + j] = sbuf[lo + j];
  }
}

// 8 blocks per 1024-node bucket: block (b,sub) owns local nodes [sub*128, +128).
// One counting pass computes BOTH the prefix (# entries below the sub-range)
// and per-node counts; then scan + scatter. 784 blocks -> full GPU.
__global__ __launch_bounds__(256) void sb_csr8(const int* __restrict__ bstart,
                                               const int* __restrict__ ebuf,
                                               int* __restrict__ col,
                                               int* __restrict__ rowptr,
                                               int N, int E) {
  __shared__ int cnt[128], off[128];
  __shared__ int pref_sh;
  int idx = blockIdx.x;
  int b = idx >> 3, sub = idx & 7;
  int t = threadIdx.x;
  int s = bstart[b], e = bstart[b + 1];
  int lo = sub * 128, hi = lo + 128;
  if (t < 128) cnt[t] = 0;
  if (t == 0) pref_sh = 0;
  __syncthreads();

  int myPref = 0;
  for (int j = s + t; j < e; j += 256) {
    int nl = (ebuf[j] >> 17) & (BKN - 1);
    if (nl < lo) myPref++;
    else if (nl < hi) atomicAdd(&cnt[nl - lo], 1);
  }
#pragma unroll
  for (int m = 1; m < 64; m <<= 1) myPref += __shfl_xor(myPref, m, 64);
  if ((t & 63) == 0 && myPref) atomicAdd(&pref_sh, myPref);
  __syncthreads();

  int base = s + pref_sh;
  if (t < 64) {  // wave 0 scans cnt[128]
    int v0 = cnt[2 * t], v1 = cnt[2 * t + 1];
    int ss = v0 + v1, inc = ss;
#pragma unroll
    for (int m = 1; m < 64; m <<= 1) {
      int u = __shfl_up(inc, m, 64);
      if (t >= m) inc += u;
    }
    int ex = inc - ss;
    off[2 * t] = ex; off[2 * t + 1] = ex + v0;
  }
  __syncthreads();

  int nbase = (b << BKSH) + lo;
  if (t < 128) {
    int node = nbase + t;
    if (node < N) rowptr[node] = base + off[t];
    cnt[t] = 0;  // reuse as cursor
  }
  __syncthreads();
  for (int j = s + t; j < e; j += 256) {
    int v = ebuf[j];
    int nl = (v >> 17) & (BKN - 1);
    if (nl >= lo && nl < hi) {
      int p = atomicAdd(&cnt[nl - lo], 1);
      col[base + off[nl - lo] + p] = v & 0x1FFFF;
    }
  }
  if (idx == 0 && t == 0) rowptr[N] = E;
}

// One wave per node on bf16 rows (128B). Lane = (oct o, slot d): oct o handles
// edges j = s+o, s+o+8, ...; one dwordx4 instruction covers 8 edges (1KB total).
// fp32 accumulate, 3-round cross-oct shuffle reduce, bf16 agg write (mean folded).
__global__ __launch_bounds__(256) void gcn_gather(const unsigned short* __restrict__ xb,
                                                  const int* __restrict__ rowptr,
                                                  const int* __restrict__ col,
                                                  unsigned short* __restrict__ aggb,
                                                  int N) {
  int gid = blockIdx.x * 256 + threadIdx.x;
  int node = gid >> 6;
  if (node >= N) return;
  int lane = threadIdx.x & 63;
  int o = lane >> 3, d = lane & 7;
  int s = rowptr[node], e = rowptr[node + 1];

  float a[8] = {0.f, 0.f, 0.f, 0.f, 0.f, 0.f, 0.f, 0.f};
  float b2[8] = {0.f, 0.f, 0.f, 0.f, 0.f, 0.f, 0.f, 0.f};
  int j = s + o;
  for (; j + 8 < e; j += 16) {  // 16 edges in flight per wave
    int c0 = col[j], c1 = col[j + 8];
    short8 v0 = *(const short8*)&xb[(long long)c0 * 64 + d * 8];
    short8 v1 = *(const short8*)&xb[(long long)c1 * 64 + d * 8];
    add8(a, v0);
    add8(b2, v1);
  }
  for (; j < e; j += 8) {
    short8 v = *(const short8*)&xb[(long long)col[j] * 64 + d * 8];
    add8(a, v);
  }
#pragma unroll
  for (int k = 0; k < 8; ++k) a[k] += b2[k];

#pragma unroll
  for (int m = 8; m <= 32; m <<= 1) {
#pragma unroll
    for (int k = 0; k < 8; ++k) a[k] += __shfl_xor(a[k], m, 64);
  }

  if (o == 0) {
    float cnt = (float)(e - s);
    float inv = 1.0f / fmaxf(cnt, 1.0f);
    short8 r;
#pragma unroll
    for (int k = 0; k < 8; ++k) r[k] = (short)f2bf(a[k] * inv);
    *(short8*)&aggb[(long long)node * 64 + d * 8] = r;  // 8 lanes x 16B = 128B
  }
}

// bf16 MFMA GEMM, zero LDS. Wave w owns nodes [blk*64 + w*16, +16).
// A-frags (X, AGG) load DIRECTLY from bf16 arrays: one dwordx4 per lane per
// 32-k step. B-frags packed from fp32 W (32KB, L1/L2-hot). One accumulator:
// D = Ax*Ws^T + Aagg*Wn^T. C/D: col=lane&15, row=quad*4+reg (HW-verified).
__global__ __launch_bounds__(256) void gcn_gemm(const unsigned short* __restrict__ xb,
                                                const unsigned short* __restrict__ aggb,
                                                const float* __restrict__ Wself,
                                                const float* __restrict__ bself,
                                                const float* __restrict__ Wneigh,
                                                float* __restrict__ out, int N) {
  int lane = threadIdx.x & 63;
  int w = threadIdx.x >> 6;
  int tb = blockIdx.x * 64 + w * 16;
  int m = lane & 15, q = lane >> 4;

  long long rowA = (long long)min(tb + m, N - 1) * 64;
  short8 ax[2], aa[2];
#pragma unroll
  for (int ks = 0; ks < 2; ++ks) {
    ax[ks] = *(const short8*)&xb[rowA + ks * 32 + q * 8];
    aa[ks] = *(const short8*)&aggb[rowA + ks * 32 + q * 8];
  }

#pragma unroll
  for (int nt = 0; nt < 4; ++nt) {
    int ob = nt * 16;
    long long rowB = (long long)(ob + m) * 64;
    floatx4 acc = {0.f, 0.f, 0.f, 0.f};
#pragma unroll
    for (int ks = 0; ks < 2; ++ks) {
      const float* pw = &Wself[rowB + ks * 32 + q * 8];
      short8 bw = pack8(*(const float4*)pw, *(const float4*)(pw + 4));
      acc = __builtin_amdgcn_mfma_f32_16x16x32_bf16(ax[ks], bw, acc, 0, 0, 0);
      const float* pn = &Wneigh[rowB + ks * 32 + q * 8];
      short8 bn = pack8(*(const float4*)pn, *(const float4*)(pn + 4));
      acc = __builtin_amdgcn_mfma_f32_16x16x32_bf16(aa[ks], bn, acc, 0, 0, 0);
    }
    float bias = bself[ob + m];
#pragma unroll
    for (int r = 0; r < 4; ++r) {
      int node = tb + q * 4 + r;
      if (node < N) {
        float v = acc[r] + bias;
        out[(long long)node * 64 + ob + m] = fmaxf(v, 0.f);
      }
    }
  }
}

extern "C" void kernel_launch(void* const* d_in, const int* in_sizes, int n_in,
                              void* d_out, int out_size, void* d_ws, size_t ws_size,
                              hipStream_t stream) {
  const float* x      = (const float*)d_in[0];
  const int*   eidx   = (const int*)d_in[1];
  const float* Wself  = (const float*)d_in[2];
  const float* bself  = (const float*)d_in[3];
  const float* Wneigh = (const float*)d_in[4];
  float* out = (float*)d_out;

  const int N = in_sizes[0] / 64;
  const int E = in_sizes[1] / 2;
  const int* src = eidx;      // edge_index row 0
  const int* dst = eidx + E;  // edge_index row 1
  const int NB = (N + BKN - 1) / BKN;  // 98 buckets of 1024 nodes

  // ws layout: xb[N*64] bf16 | aggb[N*64] bf16 | gcnt[128] | cursor[128]
  //            | bstart[128] | rowptr[N+1] | ebuf[E] | col[E]   (~36 MB)
  unsigned short* xb   = (unsigned short*)d_ws;
  unsigned short* aggb = xb + (size_t)N * 64;
  int* gcnt   = (int*)(aggb + (size_t)N * 64);
  int* cursor = gcnt + MAXNB;
  int* bstart = cursor + MAXNB;
  int* rowptr = bstart + MAXNB;
  int* ebuf   = rowptr + N + 1;
  int* col    = ebuf + E;

  (void)hipMemsetAsync(gcnt, 0, MAXNB * sizeof(int), stream);

  long long nx = (long long)N * 64;
  x2bf<<<(int)((nx / 8 + 255) / 256), 256, 0, stream>>>(x, xb, nx);

  int cb = (E + CHUNK - 1) / CHUNK;  // 306 binning blocks
  bin_hist<<<cb, 256, 0, stream>>>(dst, gcnt, E, NB);
  bin_scan<<<1, 64, 0, stream>>>(gcnt, bstart, cursor, NB, E);
  bin_scatter<<<cb, 256, 0, stream>>>(src, dst, cursor, ebuf, E, NB);
  sb_csr8<<<NB * 8, 256, 0, stream>>>(bstart, ebuf, col, rowptr, N, E);
  gcn_gather<<<(int)((nx + 255) / 256), 256, 0, stream>>>(xb, rowptr, col, aggb, N);
  gcn_gemm<<<(N + 63) / 64, 256, 0, stream>>>(xb, aggb, Wself, bself, Wneigh, out, N);
}